// Round 4
// baseline (595.617 us; speedup 1.0000x reference)
//
#include <hip/hip_runtime.h>
#include <math.h>

// Problem constants (match reference)
#define NROWS 65536          // B*S = 16*4096
#define CIN   768
#define QCOUNT 524288.0      // NROWS * DDIM
#define RPW   8              // rows per wave
#define NBLK  (NROWS / (4 * RPW))   // 2048 blocks of 4 waves

// One wave processes RPW rows, A/B software pipeline.
// Lane mapping: dg = lane&7 (quantizer dim), lev = lane>>3 (codebook level).
// Wc (24KB) lives in per-lane registers (96 VGPR), filled once via swizzled LDS;
// the 24.6KB LDS buffer is then re-staged with We (read per row, linear,
// conflict-free consecutive-lane b128).
// Occupancy plan: VGPR=128 (launch_bounds(256,4)) -> 16 waves/CU; LDS 24.6KB
// -> not binding; grid 2048 blocks -> 8/CU available for 4 resident slots.

// Distributing butterfly: reduce 8 per-lane f64 partials across 64 lanes,
// delivering zc[d] to lanes with (lane&7)==d. Fixed order, static selects.
#define REDUCE_TO_MINE(da, out)                                            \
    {                                                                      \
        double k0 = b0 ? da[1] : da[0], s0 = b0 ? da[0] : da[1];           \
        double k1 = b0 ? da[3] : da[2], s1 = b0 ? da[2] : da[3];           \
        double k2 = b0 ? da[5] : da[4], s2 = b0 ? da[4] : da[5];           \
        double k3 = b0 ? da[7] : da[6], s3 = b0 ? da[6] : da[7];           \
        k0 += __shfl_xor(s0, 1); k1 += __shfl_xor(s1, 1);                  \
        k2 += __shfl_xor(s2, 1); k3 += __shfl_xor(s3, 1);                  \
        double m0 = b1 ? k1 : k0, t0 = b1 ? k0 : k1;                       \
        double m1 = b1 ? k3 : k2, t1 = b1 ? k2 : k3;                       \
        m0 += __shfl_xor(t0, 2); m1 += __shfl_xor(t1, 2);                  \
        double r = b2 ? m1 : m0, tq = b2 ? m0 : m1;                        \
        r += __shfl_xor(tq, 4);                                            \
        r += __shfl_xor(r, 8);                                             \
        r += __shfl_xor(r, 16);                                            \
        r += __shfl_xor(r, 32);                                            \
        out = r;                                                           \
    }

// Load one row's z (3 coalesced float4) + u (coalesced permuted 256B)
#define LOADZ(B, row)                                                      \
    B##0 = z4[(size_t)(row) * 192 + lane];                                 \
    B##1 = z4[(size_t)(row) * 192 + lane + 64];                           \
    B##2 = z4[(size_t)(row) * 192 + lane + 128];                          \
    B##u = u[(size_t)(row) * 64 + dg * 8 + lev];

// compress: zc = z @ Wc (+bc). f32 FMA within 4-chunk, f64 chunk accum —
// EXACT same arithmetic order as the verified absmax-0.0 kernel.
#define COMPRESS(B, ZCOUT)                                                 \
    {                                                                      \
        double da[8];                                                      \
        _Pragma("unroll") for (int d = 0; d < 8; ++d) da[d] = 0.0;         \
        _Pragma("unroll") for (int j = 0; j < 3; ++j) {                    \
            const float4 zv = (j == 0) ? B##0 : (j == 1) ? B##1 : B##2;    \
            float f[8];                                                    \
            _Pragma("unroll") for (int d = 0; d < 8; ++d) f[d] = 0.f;      \
            _Pragma("unroll") for (int k = 0; k < 4; ++k) {                \
                const float a = (k==0)?zv.x:(k==1)?zv.y:(k==2)?zv.z:zv.w;  \
                const float4 wA = wcA[j][k];                               \
                const float4 wB = wcB[j][k];                               \
                f[0]=fmaf(a,wA.x,f[0]); f[1]=fmaf(a,wA.y,f[1]);            \
                f[2]=fmaf(a,wA.z,f[2]); f[3]=fmaf(a,wA.w,f[3]);            \
                f[4]=fmaf(a,wB.x,f[4]); f[5]=fmaf(a,wB.y,f[5]);            \
                f[6]=fmaf(a,wB.z,f[6]); f[7]=fmaf(a,wB.w,f[7]);            \
            }                                                              \
            _Pragma("unroll") for (int d = 0; d < 8; ++d)                  \
                da[d] += (double)f[d];                                     \
        }                                                                  \
        REDUCE_TO_MINE(da, ZCOUT)                                         \
        ZCOUT += bc_mine;                                                  \
    }

// gumbel + argmax + qerr-accumulate + expand + store for one row
#define FINISH(row, ZC, UVF)                                               \
    {                                                                      \
        const double uv = (double)(UVF) + 1e-10;                           \
        const double g  = -log(-log(uv));                                  \
        double n  = g - fabs(ZC - (double)cb_mine);   /* TAU = 1 */        \
        int    li = lev;                                                   \
        float  ci = cb_mine;                                               \
        _Pragma("unroll") for (int s = 8; s <= 32; s <<= 1) {              \
            const double on = __shfl_xor(n, s);                            \
            const int    ol = __shfl_xor(li, s);                           \
            const float  oc = __shfl_xor(ci, s);                           \
            const bool   t  = (on > n) || (on == n && ol < li);            \
            n = t ? on : n; li = t ? ol : li; ci = t ? oc : ci;            \
        }                                                                  \
        const double e = ZC - (double)ci;                                  \
        qa += e * e;                                                       \
        float code[8];                                                     \
        _Pragma("unroll") for (int d = 0; d < 8; ++d)                      \
            code[d] = __shfl(ci, (lane & 56) | d);                         \
        _Pragma("unroll") for (int j = 0; j < 3; ++j) {                    \
            const int fi = lane + 64 * j;                                  \
            float4 o = beR[j];                                             \
            _Pragma("unroll") for (int d = 0; d < 8; ++d) {                \
                const float4 wv = lds_w[d * 192 + fi];                     \
                o.x = fmaf(code[d], wv.x, o.x);                            \
                o.y = fmaf(code[d], wv.y, o.y);                            \
                o.z = fmaf(code[d], wv.z, o.z);                            \
                o.w = fmaf(code[d], wv.w, o.w);                            \
            }                                                              \
            zq4[(size_t)(row) * 192 + fi] = o;                             \
        }                                                                  \
    }

template <int USE_BPART>
__global__ __launch_bounds__(256, 4) void fsq_main(
    const float* __restrict__ z, const float* __restrict__ u,
    const float* __restrict__ Wc, const float* __restrict__ bc,
    const float* __restrict__ We, const float* __restrict__ be,
    const float* __restrict__ cb, float* __restrict__ zq,
    double* __restrict__ bpart)
{
    __shared__ float4 lds_w[1536];   // holds Wc (swizzled) then We (linear)
    __shared__ double wsum[4];

    const int lane = threadIdx.x & 63;
    const int wid  = threadIdx.x >> 6;
    const int dg   = lane & 7;
    const int lev  = lane >> 3;

    // ---- stage Wc into LDS, XOR-swizzled (idx ^ ((idx>>3)&7), involution) ----
    // Stage-write: consecutive t -> bank-groups permuted within each 8 ->
    // conflict-free. Fill-read below: lanes spread over all 8 bank-groups.
    {
        const float4* __restrict__ Wc4 = (const float4*)Wc;
        for (int t = threadIdx.x; t < 1536; t += 256)
            lds_w[t ^ ((t >> 3) & 7)] = Wc4[t];
    }
    __syncthreads();

    // ---- one-time per-lane register fill: Wc rows 4*fi .. 4*fi+3 ----
    float4 wcA[3][4], wcB[3][4];
#pragma unroll
    for (int j = 0; j < 3; ++j) {
        const int fi = lane + 64 * j;
#pragma unroll
        for (int k = 0; k < 4; ++k) {
            const int a0 = 8 * fi + 2 * k;           // linear float4 idx of Wc row, d0-3
            wcA[j][k] = lds_w[a0 ^ (fi & 7)];        // s(a0): (a0>>3)==fi
            wcB[j][k] = lds_w[(a0 + 1) ^ (fi & 7)];  // d4-7
        }
    }
    __syncthreads();

    // ---- re-stage same LDS buffer with We (linear layout) ----
    {
        const float4* __restrict__ We4 = (const float4*)We;
        for (int t = threadIdx.x; t < 1536; t += 256) lds_w[t] = We4[t];
    }
    __syncthreads();

    float4 beR[3];
    {
        const float4* __restrict__ be4 = (const float4*)be;
#pragma unroll
        for (int j = 0; j < 3; ++j) beR[j] = be4[lane + 64 * j];
    }
    const float  cb_mine = cb[dg * 8 + lev];
    const double bc_mine = (double)bc[dg];
    const int b0 = lane & 1, b1 = (lane >> 1) & 1, b2 = (lane >> 2) & 1;

    const float4* __restrict__ z4 = (const float4*)z;
    float4* __restrict__ zq4 = (float4*)zq;

    const int wbase = (blockIdx.x * 4 + wid) * RPW;
    double qa = 0.0;

    // ---- row loop: 2 rows per trip, A/B software pipeline ----
    float4 zA0, zA1, zA2, zB0, zB1, zB2;
    float  zAu, zBu;
    double zcA, zcB;
    LOADZ(zA, wbase)
#pragma unroll 1
    for (int itp = 0; itp < RPW / 2; ++itp) {
        const int r0 = wbase + 2 * itp;
        LOADZ(zB, r0 + 1)                 // issue early: hides under COMPRESS+FINISH(A)
        COMPRESS(zA, zcA)
        const float uvA = zAu;
        FINISH(r0, zcA, uvA)
        COMPRESS(zB, zcB)
        const float uvB = zBu;
        if (itp != RPW / 2 - 1) { LOADZ(zA, r0 + 2) }  // prefetch next trip
        FINISH(r0 + 1, zcB, uvB)
    }

    // ---- quantization error: dg-reduce once per wave ----
    qa += __shfl_xor(qa, 1);
    qa += __shfl_xor(qa, 2);
    qa += __shfl_xor(qa, 4);
    if (USE_BPART) {
        if (lane == 0) wsum[wid] = qa;
        __syncthreads();
        if (threadIdx.x == 0)
            bpart[blockIdx.x] = (wsum[0] + wsum[1]) + (wsum[2] + wsum[3]);
    } else {
        if (lane == 0) atomicAdd(bpart, qa);
    }
}

// Deterministic fixed-order reduction of NBLK partials -> mean -> out.
__global__ __launch_bounds__(256) void fsq_tail_bpart(
    const double* __restrict__ bpart, float* __restrict__ out)
{
    __shared__ double s[256];
    const int t = threadIdx.x;
    double a = 0.0;
    for (int i = 0; i < NBLK / 256; ++i)          // fixed order
        a += bpart[t * (NBLK / 256) + i];
    s[t] = a;
    __syncthreads();
    for (int w = 128; w > 0; w >>= 1) {
        if (t < w) s[t] += s[t + w];
        __syncthreads();
    }
    if (t == 0) out[0] = (float)(s[0] * (1.0 / QCOUNT));
}

__global__ void fsq_tail_atomic(const double* __restrict__ qacc, float* __restrict__ out)
{
    out[0] = (float)(qacc[0] * (1.0 / QCOUNT));
}

extern "C" void kernel_launch(void* const* d_in, const int* in_sizes, int n_in,
                              void* d_out, int out_size, void* d_ws, size_t ws_size,
                              hipStream_t stream)
{
    const float* z  = (const float*)d_in[0];
    const float* u  = (const float*)d_in[1];
    const float* Wc = (const float*)d_in[2];
    const float* bc = (const float*)d_in[3];
    const float* We = (const float*)d_in[4];
    const float* be = (const float*)d_in[5];
    const float* cb = (const float*)d_in[6];
    // d_in[7] = codebook_mask: all levels == 8 -> mask all true, unused.

    float*  zq    = (float*)d_out;
    double* bpart = (double*)d_ws;

    if (ws_size >= (size_t)NBLK * sizeof(double)) {
        // no memset needed: every block overwrites its own slot
        fsq_main<1><<<dim3(NBLK), dim3(256), 0, stream>>>(z, u, Wc, bc, We, be, cb, zq, bpart);
        fsq_tail_bpart<<<dim3(1), dim3(256), 0, stream>>>(bpart, zq + (size_t)NROWS * CIN);
    } else {
        hipMemsetAsync(d_ws, 0, sizeof(double), stream);
        fsq_main<0><<<dim3(NBLK), dim3(256), 0, stream>>>(z, u, Wc, bc, We, be, cb, zq, bpart);
        fsq_tail_atomic<<<dim3(1), dim3(1), 0, stream>>>(bpart, zq + (size_t)NROWS * CIN);
    }
}

// Round 5
// 162.068 us; speedup vs baseline: 3.6751x; 3.6751x over previous
//
#include <hip/hip_runtime.h>
#include <math.h>

// Problem constants (match reference)
#define NROWS 65536          // B*S = 16*4096
#define CIN   768
#define QCOUNT 524288.0      // NROWS * DDIM
#define RPW   4              // rows per wave
#define NBLK  (NROWS / (4 * RPW))   // 4096 blocks of 4 waves

// One wave processes RPW rows, A/B software pipeline.
// Lane mapping: dg = lane&7 (quantizer dim), lev = lane>>3 (codebook level).
// Wc (24KB) lives in XOR-swizzled LDS, read per row (conflict-free b128).
// We read from GLOBAL, coalesced 1KB/wave-instr (L1/L2-hot) — the R2 pattern
// that was never the bottleneck. NO weight registers (R3/R4 post-mortem:
// 96-VGPR weight array either caps occupancy at 4 waves/SIMD or spills).

// Distributing butterfly: reduce 8 per-lane f64 partials across 64 lanes,
// delivering zc[d] to lanes with (lane&7)==d. Fixed order, static selects.
#define REDUCE_TO_MINE(da, out)                                            \
    {                                                                      \
        double k0 = b0 ? da[1] : da[0], s0 = b0 ? da[0] : da[1];           \
        double k1 = b0 ? da[3] : da[2], s1 = b0 ? da[2] : da[3];           \
        double k2 = b0 ? da[5] : da[4], s2 = b0 ? da[4] : da[5];           \
        double k3 = b0 ? da[7] : da[6], s3 = b0 ? da[6] : da[7];           \
        k0 += __shfl_xor(s0, 1); k1 += __shfl_xor(s1, 1);                  \
        k2 += __shfl_xor(s2, 1); k3 += __shfl_xor(s3, 1);                  \
        double m0 = b1 ? k1 : k0, t0 = b1 ? k0 : k1;                       \
        double m1 = b1 ? k3 : k2, t1 = b1 ? k2 : k3;                       \
        m0 += __shfl_xor(t0, 2); m1 += __shfl_xor(t1, 2);                  \
        double r = b2 ? m1 : m0, tq = b2 ? m0 : m1;                        \
        r += __shfl_xor(tq, 4);                                            \
        r += __shfl_xor(r, 8);                                             \
        r += __shfl_xor(r, 16);                                            \
        r += __shfl_xor(r, 32);                                            \
        out = r;                                                           \
    }

// Load one row's z (3 coalesced float4) + u (coalesced permuted 256B)
#define LOADZ(B, row)                                                      \
    B##0 = z4[(size_t)(row) * 192 + lane];                                 \
    B##1 = z4[(size_t)(row) * 192 + lane + 64];                           \
    B##2 = z4[(size_t)(row) * 192 + lane + 128];                          \
    B##u = u[(size_t)(row) * 64 + dg * 8 + lev];

// compress: zc = z @ Wc (+bc). f32 FMA within 4-chunk, f64 chunk accum —
// EXACT same arithmetic order as the verified absmax-0.0 kernel; wA/wB now
// sourced from swizzled LDS instead of registers (same values).
#define COMPRESS(B, ZCOUT)                                                 \
    {                                                                      \
        double da[8];                                                      \
        _Pragma("unroll") for (int d = 0; d < 8; ++d) da[d] = 0.0;         \
        _Pragma("unroll") for (int j = 0; j < 3; ++j) {                    \
            const float4 zv = (j == 0) ? B##0 : (j == 1) ? B##1 : B##2;    \
            const int fi = lane + 64 * j;                                  \
            const int sw = fi & 7;                                         \
            float f[8];                                                    \
            _Pragma("unroll") for (int d = 0; d < 8; ++d) f[d] = 0.f;      \
            _Pragma("unroll") for (int k = 0; k < 4; ++k) {                \
                const float a = (k==0)?zv.x:(k==1)?zv.y:(k==2)?zv.z:zv.w;  \
                const int a0 = 8 * fi + 2 * k;                             \
                const float4 wA = lds_w[a0 ^ sw];                          \
                const float4 wB = lds_w[(a0 + 1) ^ sw];                    \
                f[0]=fmaf(a,wA.x,f[0]); f[1]=fmaf(a,wA.y,f[1]);            \
                f[2]=fmaf(a,wA.z,f[2]); f[3]=fmaf(a,wA.w,f[3]);            \
                f[4]=fmaf(a,wB.x,f[4]); f[5]=fmaf(a,wB.y,f[5]);            \
                f[6]=fmaf(a,wB.z,f[6]); f[7]=fmaf(a,wB.w,f[7]);            \
            }                                                              \
            _Pragma("unroll") for (int d = 0; d < 8; ++d)                  \
                da[d] += (double)f[d];                                     \
        }                                                                  \
        REDUCE_TO_MINE(da, ZCOUT)                                         \
        ZCOUT += bc_mine;                                                  \
    }

// gumbel + argmax + qerr-accumulate + expand(We from global) + store
#define FINISH(row, ZC, UVF)                                               \
    {                                                                      \
        const double uv = (double)(UVF) + 1e-10;                           \
        const double g  = -log(-log(uv));                                  \
        double n  = g - fabs(ZC - (double)cb_mine);   /* TAU = 1 */        \
        int    li = lev;                                                   \
        float  ci = cb_mine;                                               \
        _Pragma("unroll") for (int s = 8; s <= 32; s <<= 1) {              \
            const double on = __shfl_xor(n, s);                            \
            const int    ol = __shfl_xor(li, s);                           \
            const float  oc = __shfl_xor(ci, s);                           \
            const bool   t  = (on > n) || (on == n && ol < li);            \
            n = t ? on : n; li = t ? ol : li; ci = t ? oc : ci;            \
        }                                                                  \
        const double e = ZC - (double)ci;                                  \
        qa += e * e;                                                       \
        float code[8];                                                     \
        _Pragma("unroll") for (int d = 0; d < 8; ++d)                      \
            code[d] = __shfl(ci, (lane & 56) | d);                         \
        _Pragma("unroll") for (int j = 0; j < 3; ++j) {                    \
            const int fi = lane + 64 * j;                                  \
            float4 o = beR[j];                                             \
            _Pragma("unroll") for (int d = 0; d < 8; ++d) {                \
                const float4 wv = We4[d * 192 + fi];                       \
                o.x = fmaf(code[d], wv.x, o.x);                            \
                o.y = fmaf(code[d], wv.y, o.y);                            \
                o.z = fmaf(code[d], wv.z, o.z);                            \
                o.w = fmaf(code[d], wv.w, o.w);                            \
            }                                                              \
            zq4[(size_t)(row) * 192 + fi] = o;                             \
        }                                                                  \
    }

template <int USE_BPART>
__global__ __launch_bounds__(256) void fsq_main(
    const float* __restrict__ z, const float* __restrict__ u,
    const float* __restrict__ Wc, const float* __restrict__ bc,
    const float* __restrict__ We, const float* __restrict__ be,
    const float* __restrict__ cb, float* __restrict__ zq,
    double* __restrict__ bpart)
{
    __shared__ float4 lds_w[1536];   // Wc, XOR-swizzled
    __shared__ double wsum[4];

    const int lane = threadIdx.x & 63;
    const int wid  = threadIdx.x >> 6;
    const int dg   = lane & 7;
    const int lev  = lane >> 3;

    // ---- stage Wc into LDS, XOR-swizzled (idx ^ ((idx>>3)&7), involution) ----
    {
        const float4* __restrict__ Wc4 = (const float4*)Wc;
        for (int t = threadIdx.x; t < 1536; t += 256)
            lds_w[t ^ ((t >> 3) & 7)] = Wc4[t];
    }

    float4 beR[3];
    {
        const float4* __restrict__ be4 = (const float4*)be;
#pragma unroll
        for (int j = 0; j < 3; ++j) beR[j] = be4[lane + 64 * j];
    }
    const float  cb_mine = cb[dg * 8 + lev];
    const double bc_mine = (double)bc[dg];
    const int b0 = lane & 1, b1 = (lane >> 1) & 1, b2 = (lane >> 2) & 1;

    const float4* __restrict__ z4  = (const float4*)z;
    const float4* __restrict__ We4 = (const float4*)We;
    float4* __restrict__ zq4 = (float4*)zq;

    const int wbase = (blockIdx.x * 4 + wid) * RPW;
    double qa = 0.0;

    __syncthreads();   // Wc image ready

    // ---- row loop: 2 rows per trip, A/B software pipeline ----
    float4 zA0, zA1, zA2, zB0, zB1, zB2;
    float  zAu, zBu;
    double zcA, zcB;
    LOADZ(zA, wbase)
#pragma unroll 1
    for (int itp = 0; itp < RPW / 2; ++itp) {
        const int r0 = wbase + 2 * itp;
        LOADZ(zB, r0 + 1)                 // issue early: hides under COMPRESS+FINISH(A)
        COMPRESS(zA, zcA)
        const float uvA = zAu;
        FINISH(r0, zcA, uvA)
        COMPRESS(zB, zcB)
        const float uvB = zBu;
        if (itp != RPW / 2 - 1) { LOADZ(zA, r0 + 2) }  // prefetch next trip
        FINISH(r0 + 1, zcB, uvB)
    }

    // ---- quantization error: dg-reduce once per wave ----
    qa += __shfl_xor(qa, 1);
    qa += __shfl_xor(qa, 2);
    qa += __shfl_xor(qa, 4);
    if (USE_BPART) {
        if (lane == 0) wsum[wid] = qa;
        __syncthreads();
        if (threadIdx.x == 0)
            bpart[blockIdx.x] = (wsum[0] + wsum[1]) + (wsum[2] + wsum[3]);
    } else {
        if (lane == 0) atomicAdd(bpart, qa);
    }
}

// Deterministic fixed-order reduction of NBLK partials -> mean -> out.
__global__ __launch_bounds__(256) void fsq_tail_bpart(
    const double* __restrict__ bpart, float* __restrict__ out)
{
    __shared__ double s[256];
    const int t = threadIdx.x;
    double a = 0.0;
    for (int i = 0; i < NBLK / 256; ++i)          // fixed order
        a += bpart[t * (NBLK / 256) + i];
    s[t] = a;
    __syncthreads();
    for (int w = 128; w > 0; w >>= 1) {
        if (t < w) s[t] += s[t + w];
        __syncthreads();
    }
    if (t == 0) out[0] = (float)(s[0] * (1.0 / QCOUNT));
}

__global__ void fsq_tail_atomic(const double* __restrict__ qacc, float* __restrict__ out)
{
    out[0] = (float)(qacc[0] * (1.0 / QCOUNT));
}

extern "C" void kernel_launch(void* const* d_in, const int* in_sizes, int n_in,
                              void* d_out, int out_size, void* d_ws, size_t ws_size,
                              hipStream_t stream)
{
    const float* z  = (const float*)d_in[0];
    const float* u  = (const float*)d_in[1];
    const float* Wc = (const float*)d_in[2];
    const float* bc = (const float*)d_in[3];
    const float* We = (const float*)d_in[4];
    const float* be = (const float*)d_in[5];
    const float* cb = (const float*)d_in[6];
    // d_in[7] = codebook_mask: all levels == 8 -> mask all true, unused.

    float*  zq    = (float*)d_out;
    double* bpart = (double*)d_ws;

    if (ws_size >= (size_t)NBLK * sizeof(double)) {
        // no memset needed: every block overwrites its own slot
        fsq_main<1><<<dim3(NBLK), dim3(256), 0, stream>>>(z, u, Wc, bc, We, be, cb, zq, bpart);
        fsq_tail_bpart<<<dim3(1), dim3(256), 0, stream>>>(bpart, zq + (size_t)NROWS * CIN);
    } else {
        hipMemsetAsync(d_ws, 0, sizeof(double), stream);
        fsq_main<0><<<dim3(NBLK), dim3(256), 0, stream>>>(z, u, Wc, bc, We, be, cb, zq, bpart);
        fsq_tail_atomic<<<dim3(1), dim3(1), 0, stream>>>(bpart, zq + (size_t)NROWS * CIN);
    }
}